// Round 3
// baseline (481.630 us; speedup 1.0000x reference)
//
#include <hip/hip_runtime.h>

#define NB 32
#define NPTS 1024
#define NP 256
#define NS 16
#define NC 256
#define NH 128
#define NOUT 97
#define GTN 16

// ---------------------------------------------------------------------------
// Prep: w0ft[c][o] = sa_w0[o][3+c]; w0x[d][o] = sa_w0[o][d];
// quad layouts wq[(c4*128+o)*4+k] = W[o][c4*4+k]  -> one dwordx4 per c4-step.
// ---------------------------------------------------------------------------
__global__ __launch_bounds__(256) void prep_kernel(
    const float* __restrict__ sa_w0, const float* __restrict__ sa_w1,
    const float* __restrict__ sa_w2, const float* __restrict__ fc_w1,
    const float* __restrict__ fc_w2, const float* __restrict__ fc_w3,
    float* __restrict__ w0ft, float* __restrict__ w0x,
    float* __restrict__ w1q, float* __restrict__ w2q,
    float* __restrict__ fq1, float* __restrict__ fq2,
    float* __restrict__ w3q)
{
  int t = blockIdx.x * 256 + threadIdx.x;
  if (t < 256 * 128) { int c = t >> 7, o = t & 127; w0ft[t] = sa_w0[o * 259 + 3 + c]; }
  if (t < 3 * 128)   { int d = t >> 7, o = t & 127; w0x[t]  = sa_w0[o * 259 + d]; }
  if (t < 128 * 128) {
    int c = t >> 7, o = t & 127;
    int qi = ((c >> 2) * 128 + o) * 4 + (c & 3);
    w1q[qi] = sa_w1[o * 128 + c];
    w2q[qi] = sa_w2[o * 128 + c];
    fq1[qi] = fc_w1[o * 128 + c];
    fq2[qi] = fc_w2[o * 128 + c];
    w3q[qi] = (o < NOUT) ? fc_w3[o * 128 + c] : 0.0f;
  }
}

// ---------------------------------------------------------------------------
// Fused FPS + gfeat (unchanged from passing round-2 version).
//   blocks [0, NB):      FPS, one 64-lane wave per batch.
//   blocks [NB, NB+2048): G[b][n][o] = sum_c features[b][c][n] * w0ft[c][o]
// ---------------------------------------------------------------------------
__global__ __launch_bounds__(128) void fused_fps_gfeat_kernel(
    const float* __restrict__ xyz, int* __restrict__ inds,
    const float* __restrict__ features, const float* __restrict__ w0ft,
    float* __restrict__ G)
{
  __shared__ __align__(16) float smem[NC * 20];

  if (blockIdx.x < NB) {
    if (threadIdx.x >= 64) return;                // single wave
    const int b = blockIdx.x;
    const int lane = threadIdx.x;
    float* s_x = smem;
    float* s_y = smem + NPTS;
    float* s_z = smem + 2 * NPTS;
    const float* xb = xyz + b * NPTS * 3;

    float pts[48];
    const float4* src = reinterpret_cast<const float4*>(xb + lane * 48);
#pragma unroll
    for (int r = 0; r < 12; ++r) {
      float4 v = src[r];
      pts[4 * r + 0] = v.x; pts[4 * r + 1] = v.y;
      pts[4 * r + 2] = v.z; pts[4 * r + 3] = v.w;
    }
    float dist[16];
#pragma unroll
    for (int j = 0; j < 16; ++j) {
      s_x[lane * 16 + j] = pts[3 * j + 0];
      s_y[lane * 16 + j] = pts[3 * j + 1];
      s_z[lane * 16 + j] = pts[3 * j + 2];
      dist[j] = 1e10f;
    }
    int far = 0;
    for (int i = 0; i < NP; ++i) {
      if (lane == 0) inds[b * NP + i] = far;
      float cx = s_x[far], cy = s_y[far], cz = s_z[far];
      float bv = -1.0f; int bi = 0;
#pragma unroll
      for (int j = 0; j < 16; ++j) {
#pragma clang fp contract(off)
        float dx = pts[3 * j + 0] - cx;
        float dy = pts[3 * j + 1] - cy;
        float dz = pts[3 * j + 2] - cz;
        float d = (dx * dx + dy * dy) + dz * dz;
        float nd = fminf(dist[j], d);
        dist[j] = nd;
        if (nd > bv) { bv = nd; bi = lane * 16 + j; }
      }
#pragma unroll
      for (int off = 1; off < 64; off <<= 1) {
        float ov = __shfl_xor(bv, off);
        int   oi = __shfl_xor(bi, off);
        if (ov > bv || (ov == bv && oi < bi)) { bv = ov; bi = oi; }
      }
      far = bi;
    }
    return;
  }

  const int blk = blockIdx.x - NB;
  const int b  = blk >> 6;
  const int n0 = (blk & 63) * GTN;
  const int o  = threadIdx.x;
  float* ft = smem;
  const float* fb = features + b * NC * NPTS;
#pragma unroll
  for (int r = 0; r < 2; ++r) {
    int c = r * 128 + o;
    const float4* srcf = reinterpret_cast<const float4*>(fb + c * NPTS + n0);
    float4 v0 = srcf[0], v1 = srcf[1], v2 = srcf[2], v3 = srcf[3];
    *reinterpret_cast<float4*>(&ft[c * 20 + 0])  = v0;
    *reinterpret_cast<float4*>(&ft[c * 20 + 4])  = v1;
    *reinterpret_cast<float4*>(&ft[c * 20 + 8])  = v2;
    *reinterpret_cast<float4*>(&ft[c * 20 + 12]) = v3;
  }
  __syncthreads();
  float acc[GTN];
#pragma unroll
  for (int j = 0; j < GTN; ++j) acc[j] = 0.0f;
  for (int c = 0; c < NC; ++c) {
    float w = w0ft[c * 128 + o];
    float4 v0 = *reinterpret_cast<const float4*>(&ft[c * 20 + 0]);
    float4 v1 = *reinterpret_cast<const float4*>(&ft[c * 20 + 4]);
    float4 v2 = *reinterpret_cast<const float4*>(&ft[c * 20 + 8]);
    float4 v3 = *reinterpret_cast<const float4*>(&ft[c * 20 + 12]);
    acc[0]  += w * v0.x; acc[1]  += w * v0.y; acc[2]  += w * v0.z; acc[3]  += w * v0.w;
    acc[4]  += w * v1.x; acc[5]  += w * v1.y; acc[6]  += w * v1.z; acc[7]  += w * v1.w;
    acc[8]  += w * v2.x; acc[9]  += w * v2.y; acc[10] += w * v2.z; acc[11] += w * v2.w;
    acc[12] += w * v3.x; acc[13] += w * v3.y; acc[14] += w * v3.z; acc[15] += w * v3.w;
  }
#pragma unroll
  for (int j = 0; j < GTN; ++j)
    G[(b * NPTS + n0 + j) * NH + o] = acc[j];
}

// ---------------------------------------------------------------------------
// Main fused kernel: one block (128 thr) per (b, p).
// Prologue (wave 0): ball query, bit-identical to the previously-passing
// ball_kernel; writes idxs/gxs straight to LDS (no nbr buffer).
// Body: j in two halves of 8 (LDS 17.9KB -> 9.3KB => 16 blocks/CU),
// maxpool is a running register max. Weight loads are one dwordx4 per c4.
// ---------------------------------------------------------------------------
__global__ __launch_bounds__(128) void main_kernel(
    const float* __restrict__ xyz, const int* __restrict__ inds,
    const float* __restrict__ G,
    const float* __restrict__ w0x, const float* __restrict__ s0v, const float* __restrict__ t0v,
    const float* __restrict__ w1q, const float* __restrict__ s1v, const float* __restrict__ t1v,
    const float* __restrict__ w2q, const float* __restrict__ s2v, const float* __restrict__ t2v,
    const float* __restrict__ fq1, const float* __restrict__ fs1, const float* __restrict__ ft1,
    const float* __restrict__ fq2, const float* __restrict__ fs2, const float* __restrict__ ft2,
    const float* __restrict__ w3q, const float* __restrict__ b3, float* __restrict__ out)
{
  const int bid = blockIdx.x;           // == b*NP + p
  const int b = bid >> 8;
  const int p = bid & 255;
  const int o = threadIdx.x;
  __shared__ __align__(16) float x1[8][NH];
  __shared__ __align__(16) float x2[8][NH];
  __shared__ __align__(16) float fsh[NH];
  __shared__ __align__(16) float hsh[NH];
  __shared__ float gxs[NS][3];
  __shared__ int   idxs[NS];

  const float* xb = xyz + b * NPTS * 3;

  // ---- fused ball query on wave 0 ----
  if (o < 64) {
    const int lane = o;
    const int ci = inds[bid];
    const float cx = xb[ci * 3 + 0], cy = xb[ci * 3 + 1], cz = xb[ci * 3 + 2];
    float nq;
    {
#pragma clang fp contract(off)
      nq = (cx * cx + cy * cy) + cz * cz;
    }
    const float R2 = 0.09f;
    unsigned mask = 0;
    int cnt = 0, firstn = NPTS;
    for (int j = 0; j < 16; ++j) {
#pragma clang fp contract(off)
      int n = lane * 16 + j;     // lane-major: global order == lexicographic
      float x = xb[n * 3 + 0], y = xb[n * 3 + 1], z = xb[n * 3 + 2];
      float nx = (x * x + y * y) + z * z;
      float dt = (cx * x + cy * y) + cz * z;
      float d2 = (nq + nx) - 2.0f * dt;
      if (d2 < R2) { mask |= 1u << j; ++cnt; if (firstn == NPTS) firstn = n; }
    }
    int inc = cnt;
    for (int off = 1; off < 64; off <<= 1) {
      int v = __shfl_up(inc, off);
      if (lane >= off) inc += v;
    }
    int rank  = inc - cnt;
    int total = __shfl(inc, 63);
    for (int j = 0; j < 16; ++j) {
      if (mask & (1u << j)) {
        if (rank < NS) {
          int n = lane * 16 + j;
          idxs[rank] = n;
          float x = xb[n * 3 + 0], y = xb[n * 3 + 1], z = xb[n * 3 + 2];
          gxs[rank][0] = (x - cx) / 0.3f;
          gxs[rank][1] = (y - cy) / 0.3f;
          gxs[rank][2] = (z - cz) / 0.3f;
        }
        ++rank;
      }
    }
    int fmin = firstn;
    for (int off2 = 32; off2 > 0; off2 >>= 1) {
      int ov = __shfl_xor(fmin, off2);
      fmin = min(fmin, ov);
    }
    if (lane < NS && lane >= total) {
      idxs[lane] = fmin;
      float x = xb[fmin * 3 + 0], y = xb[fmin * 3 + 1], z = xb[fmin * 3 + 2];
      gxs[lane][0] = (x - cx) / 0.3f;
      gxs[lane][1] = (y - cy) / 0.3f;
      gxs[lane][2] = (z - cz) / 0.3f;
    }
  }
  __syncthreads();

  const float wxa = w0x[o], wxb = w0x[NH + o], wxc = w0x[2 * NH + o];
  const float s0 = s0v[o], t0 = t0v[o];
  const float s1 = s1v[o], t1 = t1v[o];
  const float s2 = s2v[o], t2 = t2v[o];

  float fo = 0.0f;
  const char* x1b = (const char*)&x1[0][0];
  const char* x2b = (const char*)&x2[0][0];

  for (int half = 0; half < 2; ++half) {
    const int j0 = half * 8;
    // L0: 8 slots
#pragma unroll
    for (int j = 0; j < 8; ++j) {
      int nj = idxs[j0 + j];
      float g = G[(b * NPTS + nj) * NH + o];
      float y = g + wxa * gxs[j0 + j][0] + wxb * gxs[j0 + j][1] + wxc * gxs[j0 + j][2];
      x1[j][o] = fmaxf(y * s0 + t0, 0.0f);
    }
    __syncthreads();          // SYNC_A: x1 ready (also: prev-half L2 x2-reads done)

    // L1
    float acc[8];
#pragma unroll
    for (int j = 0; j < 8; ++j) acc[j] = 0.0f;
#pragma unroll 2
    for (int c4 = 0; c4 < 32; ++c4) {
      float4 w = reinterpret_cast<const float4*>(w1q)[c4 * 128 + o];
#pragma unroll
      for (int j = 0; j < 8; ++j) {
        float4 xv = *reinterpret_cast<const float4*>(x1b + j * 512 + c4 * 16);
        acc[j] += w.x * xv.x + w.y * xv.y + w.z * xv.z + w.w * xv.w;
      }
    }
#pragma unroll
    for (int j = 0; j < 8; ++j) x2[j][o] = fmaxf(acc[j] * s1 + t1, 0.0f);
    __syncthreads();          // SYNC_B: x2 ready; x1 reads done (next-half L0 may write)

    // L2 + running maxpool
#pragma unroll
    for (int j = 0; j < 8; ++j) acc[j] = 0.0f;
#pragma unroll 2
    for (int c4 = 0; c4 < 32; ++c4) {
      float4 w = reinterpret_cast<const float4*>(w2q)[c4 * 128 + o];
#pragma unroll
      for (int j = 0; j < 8; ++j) {
        float4 xv = *reinterpret_cast<const float4*>(x2b + j * 512 + c4 * 16);
        acc[j] += w.x * xv.x + w.y * xv.y + w.z * xv.z + w.w * xv.w;
      }
    }
#pragma unroll
    for (int j = 0; j < 8; ++j) fo = fmaxf(fo, fmaxf(acc[j] * s2 + t2, 0.0f));
  }
  fsh[o] = fo;
  __syncthreads();

  // FC1
  {
    float a = 0.0f;
#pragma unroll 4
    for (int c4 = 0; c4 < 32; ++c4) {
      float4 w = reinterpret_cast<const float4*>(fq1)[c4 * 128 + o];
      float4 fv = *reinterpret_cast<const float4*>(&fsh[c4 * 4]);
      a += w.x * fv.x + w.y * fv.y + w.z * fv.z + w.w * fv.w;
    }
    hsh[o] = fmaxf(a * fs1[o] + ft1[o], 0.0f);
  }
  __syncthreads();

  // FC2 (overwrites fsh; FC1's fsh reads completed at the barrier above)
  {
    float a = 0.0f;
#pragma unroll 4
    for (int c4 = 0; c4 < 32; ++c4) {
      float4 w = reinterpret_cast<const float4*>(fq2)[c4 * 128 + o];
      float4 hv = *reinterpret_cast<const float4*>(&hsh[c4 * 4]);
      a += w.x * hv.x + w.y * hv.y + w.z * hv.z + w.w * hv.w;
    }
    fsh[o] = fmaxf(a * fs2[o] + ft2[o], 0.0f);
  }
  __syncthreads();

  // FC3
  {
    float a = b3[o < NOUT ? o : 0];
#pragma unroll 4
    for (int c4 = 0; c4 < 32; ++c4) {
      float4 w = reinterpret_cast<const float4*>(w3q)[c4 * 128 + o];
      float4 hv = *reinterpret_cast<const float4*>(&fsh[c4 * 4]);
      a += w.x * hv.x + w.y * hv.y + w.z * hv.z + w.w * hv.w;
    }
    if (o < NOUT) out[(b * NOUT + o) * NP + p] = a;
  }
}

extern "C" void kernel_launch(void* const* d_in, const int* in_sizes, int n_in,
                              void* d_out, int out_size, void* d_ws, size_t ws_size,
                              hipStream_t stream) {
  const float* xyz      = (const float*)d_in[0];
  const float* features = (const float*)d_in[1];
  const float* sa_w0 = (const float*)d_in[2];
  const float* sa_s0 = (const float*)d_in[3];
  const float* sa_t0 = (const float*)d_in[4];
  const float* sa_w1 = (const float*)d_in[5];
  const float* sa_s1 = (const float*)d_in[6];
  const float* sa_t1 = (const float*)d_in[7];
  const float* sa_w2 = (const float*)d_in[8];
  const float* sa_s2 = (const float*)d_in[9];
  const float* sa_t2 = (const float*)d_in[10];
  const float* fc_w1 = (const float*)d_in[11];
  const float* fc_s1 = (const float*)d_in[12];
  const float* fc_t1 = (const float*)d_in[13];
  const float* fc_w2 = (const float*)d_in[14];
  const float* fc_s2 = (const float*)d_in[15];
  const float* fc_t2 = (const float*)d_in[16];
  const float* fc_w3 = (const float*)d_in[17];
  const float* fc_b3 = (const float*)d_in[18];
  float* out = (float*)d_out;

  char* ws = (char*)d_ws;
  int* inds = (int*)ws;            ws += (size_t)NB * NP * sizeof(int);
  float* w0ft = (float*)ws;        ws += (size_t)256 * 128 * sizeof(float);
  float* w0x  = (float*)ws;        ws += (size_t)3 * 128 * sizeof(float);
  float* w1q  = (float*)ws;        ws += (size_t)128 * 128 * sizeof(float);
  float* w2q  = (float*)ws;        ws += (size_t)128 * 128 * sizeof(float);
  float* fq1  = (float*)ws;        ws += (size_t)128 * 128 * sizeof(float);
  float* fq2  = (float*)ws;        ws += (size_t)128 * 128 * sizeof(float);
  float* w3q  = (float*)ws;        ws += (size_t)128 * 128 * sizeof(float);
  float* G    = (float*)ws;        ws += (size_t)NB * NPTS * NH * sizeof(float);

  prep_kernel<<<128, 256, 0, stream>>>(sa_w0, sa_w1, sa_w2, fc_w1, fc_w2, fc_w3,
                                       w0ft, w0x, w1q, w2q, fq1, fq2, w3q);
  fused_fps_gfeat_kernel<<<NB + NB * (NPTS / GTN), 128, 0, stream>>>(
      xyz, inds, features, w0ft, G);
  main_kernel<<<NB * NP, 128, 0, stream>>>(
      xyz, inds, G,
      w0x, sa_s0, sa_t0,
      w1q, sa_s1, sa_t1,
      w2q, sa_s2, sa_t2,
      fq1, fc_s1, fc_t1,
      fq2, fc_s2, fc_t2,
      w3q, fc_b3, out);
}